// Round 13
// baseline (413.794 us; speedup 1.0000x reference)
//
#include <hip/hip_runtime.h>

// nnmodel_35708358099045 R16: hardware-pinned prefetch via inline-asm loads.
// R8/R11/R14/R15 post-mortems: hipcc sank or remat'd EVERY C++-level
// prefetch/preload attempt (4 corrupted experiments). The only un-sinkable
// load is asm volatile global_load_dwordx4 with manual counted waits.
// Structure: issue ALL 30 input loads (x:10,z:20) at kernel start; consume
// with literal s_waitcnt vmcnt(20/16/12/8/4/0) + sched_barrier(0) (r263
// hoist hazard); y issued under tail emits; vmcnt(0); coalesced... full-row
// stores. Fully unrolled (vmcnt imms must be literals). No LDS. Per-wave
// MLP: ~30 lines in flight vs ~4 before. FP order bit-identical R5-R15.
// Gates: WRITE 82-86MB (spill), VGPR<=220, FETCH<=220MB.

#define HN 10
#define ND 40
#define HF 8
#define TPB 256

#define GLD(dst, addr) \
    asm volatile("global_load_dwordx4 %0, %1, off" : "=v"(dst) : "v"(addr))
#define VMWAIT(n) do { \
    asm volatile("s_waitcnt vmcnt(" #n ")"); \
    __builtin_amdgcn_sched_barrier(0); } while (0)

__global__ __launch_bounds__(TPB) void gnn_kernel(
    const float* __restrict__ x,          // [B, 40]
    const float* __restrict__ z,          // [B, 10, 8]
    const float* __restrict__ y,          // [B, 40]
    const float* __restrict__ enc_rel_w,  // [8, 1]
    const float* __restrict__ enc_rel_b,  // [8]
    const float* __restrict__ enc_root_w, // [8, 8]
    const float* __restrict__ pred_rel_w, // [8, 8]
    const float* __restrict__ pred_rel_b, // [8]
    const float* __restrict__ pred_root_w,// [8, 8]
    const float* __restrict__ dec_rel_w,  // [1, 8]
    const float* __restrict__ dec_rel_b,  // [1]
    const float* __restrict__ dec_root_w, // [1, 1]
    float* __restrict__ out,              // [B, 40]
    int B)
{
    const long long e = (long long)blockIdx.x * TPB + threadIdx.x;

    const float w = 0.8948393168143698f;  // exp(-(1/3)^2) as fp32

    const float4* xr = (const float4*)(x + e * ND);        // 10 float4
    const float4* zr = (const float4*)(z + e * (HN * HF)); // 20 float4
    const float4* yr = (const float4*)(y + e * ND);        // 10 float4
    float4*       og = (float4*)(out + e * ND);            // 10 float4

    // ---- issue ALL input loads now; HW-pinned, compiler cannot sink ----
    float4 X0, X1, X2, X3, X4, X5, X6, X7, X8, X9;
    GLD(X0, xr + 0); GLD(X1, xr + 1); GLD(X2, xr + 2); GLD(X3, xr + 3);
    GLD(X4, xr + 4); GLD(X5, xr + 5); GLD(X6, xr + 6); GLD(X7, xr + 7);
    GLD(X8, xr + 8); GLD(X9, xr + 9);
    float4 Z0, Z1, Z2, Z3, Z4, Z5, Z6, Z7, Z8, Z9,
           Z10, Z11, Z12, Z13, Z14, Z15, Z16, Z17, Z18, Z19;
    GLD(Z0,  zr +  0); GLD(Z1,  zr +  1); GLD(Z2,  zr +  2); GLD(Z3,  zr +  3);
    GLD(Z4,  zr +  4); GLD(Z5,  zr +  5); GLD(Z6,  zr +  6); GLD(Z7,  zr +  7);
    GLD(Z8,  zr +  8); GLD(Z9,  zr +  9); GLD(Z10, zr + 10); GLD(Z11, zr + 11);
    GLD(Z12, zr + 12); GLD(Z13, zr + 13); GLD(Z14, zr + 14); GLD(Z15, zr + 15);
    GLD(Z16, zr + 16); GLD(Z17, zr + 17); GLD(Z18, zr + 18); GLD(Z19, zr + 19);
    // outstanding: 30 (10 x + 20 z, in issue order)

    const float drb   = dec_rel_b[0];
    const float droot = dec_root_w[0];

    auto enc_row = [&](float aggv, float4 v0, float4 v1, float (&r)[HF]) {
        float zrow[HF] = {v0.x, v0.y, v0.z, v0.w, v1.x, v1.y, v1.z, v1.w};
        #pragma unroll
        for (int f = 0; f < HF; ++f) {
            float acc = aggv * enc_rel_w[f] + enc_rel_b[f];
            #pragma unroll
            for (int g = 0; g < HF; ++g)
                acc += zrow[g] * enc_root_w[f * HF + g];
            r[f] = fmaxf(acc, 0.0f);
        }
    };

    auto emit = [&](const float (&rm)[HF], const float (&rc)[HF],
                    const float (&rp)[HF]) -> float {
        float a2[HF];
        #pragma unroll
        for (int f = 0; f < HF; ++f)
            a2[f] = rc[f] + w * (rm[f] + rp[f]);
        float s = 0.0f;
        #pragma unroll
        for (int f = 0; f < HF; ++f) {
            float acc = pred_rel_b[f];
            #pragma unroll
            for (int g = 0; g < HF; ++g)
                acc += a2[g] * pred_rel_w[f * HF + g];
            #pragma unroll
            for (int g = 0; g < HF; ++g)
                acc += rc[g] * pred_root_w[f * HF + g];
            s += fmaxf(acc, 0.0f) * dec_rel_w[f];
        }
        return s;
    };

    auto store_out = [&](int idx, float sa, float sb, float4 yv) {
        const float pair = sa + sb + drb;
        float4 o;
        o.x = (sa + drb) + yv.x * droot;
        o.y = pair       + yv.y * droot;
        o.z = pair       + yv.z * droot;
        o.w = (sb + drb) + yv.w * droot;
        og[idx] = o;
    };

    // ---- x complete (20 z still in flight): aggs, FP order as R5-R15 ----
    VMWAIT(20);
    const float a0 = X9.y + X9.z + X9.w + X0.x + X0.y + X0.z;
    const float a1 = X0.y + X0.z + X0.w + X1.x + X1.y + X1.z;
    const float a2v= X1.y + X1.z + X1.w + X2.x + X2.y + X2.z;
    const float a3 = X2.y + X2.z + X2.w + X3.x + X3.y + X3.z;
    const float a4 = X3.y + X3.z + X3.w + X4.x + X4.y + X4.z;
    const float a5 = X4.y + X4.z + X4.w + X5.x + X5.y + X5.z;
    const float a6 = X5.y + X5.z + X5.w + X6.x + X6.y + X6.z;
    const float a7 = X6.y + X6.z + X6.w + X7.x + X7.y + X7.z;
    const float a8 = X7.y + X7.z + X7.w + X8.x + X8.y + X8.z;
    const float a9 = X8.y + X8.z + X8.w + X9.x + X9.y + X9.z;

    // ---- nodes 0,1 (z f4 0-3 complete) ----
    VMWAIT(16);
    float r0[HF], r1[HF];
    enc_row(a0, Z0, Z1, r0);
    enc_row(a1, Z2, Z3, r1);

    // ---- j=1: nodes 2,3 ; s2[1], s2[2] ----
    VMWAIT(12);
    float r2[HF], r3[HF];
    enc_row(a2v, Z4, Z5, r2);
    enc_row(a3,  Z6, Z7, r3);
    const float s1 = emit(r0, r1, r2);
    const float s2 = emit(r1, r2, r3);

    // ---- j=2: nodes 4,5 ; s2[3], s2[4] ----
    VMWAIT(8);
    float r4[HF], r5[HF];
    enc_row(a4, Z8,  Z9,  r4);
    enc_row(a5, Z10, Z11, r5);
    const float s3 = emit(r2, r3, r4);
    const float s4 = emit(r3, r4, r5);

    // ---- j=3: nodes 6,7 ; s2[5], s2[6] ----
    VMWAIT(4);
    float r6[HF], r7[HF];
    enc_row(a6, Z12, Z13, r6);
    enc_row(a7, Z14, Z15, r7);
    const float s5 = emit(r4, r5, r6);
    const float s6 = emit(r5, r6, r7);

    // ---- j=4: nodes 8,9 ; s2[7], s2[8] ----
    VMWAIT(0);
    float r8[HF], r9[HF];
    enc_row(a8, Z16, Z17, r8);
    enc_row(a9, Z18, Z19, r9);
    const float s7 = emit(r6, r7, r8);
    const float s8 = emit(r7, r8, r9);

    // ---- issue y now; its latency hides under the two tail emits ----
    float4 Y0, Y1, Y2, Y3, Y4, Y5, Y6, Y7, Y8, Y9;
    GLD(Y0, yr + 0); GLD(Y1, yr + 1); GLD(Y2, yr + 2); GLD(Y3, yr + 3);
    GLD(Y4, yr + 4); GLD(Y5, yr + 5); GLD(Y6, yr + 6); GLD(Y7, yr + 7);
    GLD(Y8, yr + 8); GLD(Y9, yr + 9);

    const float s9 = emit(r8, r9, r0);               // s2[9]
    const float s0 = emit(r9, r0, r1);               // s2[0]

    // ---- y complete; straight-line full-row stores ----
    VMWAIT(0);
    store_out(0, s0, s1, Y0);
    store_out(1, s1, s2, Y1);
    store_out(2, s2, s3, Y2);
    store_out(3, s3, s4, Y3);
    store_out(4, s4, s5, Y4);
    store_out(5, s5, s6, Y5);
    store_out(6, s6, s7, Y6);
    store_out(7, s7, s8, Y7);
    store_out(8, s8, s9, Y8);
    store_out(9, s9, s0, Y9);
}

extern "C" void kernel_launch(void* const* d_in, const int* in_sizes, int n_in,
                              void* d_out, int out_size, void* d_ws, size_t ws_size,
                              hipStream_t stream) {
    const float* x          = (const float*)d_in[0];
    const float* z          = (const float*)d_in[1];
    const float* y          = (const float*)d_in[2];
    const float* enc_rel_w  = (const float*)d_in[3];
    const float* enc_rel_b  = (const float*)d_in[4];
    const float* enc_root_w = (const float*)d_in[5];
    const float* pred_rel_w = (const float*)d_in[6];
    const float* pred_rel_b = (const float*)d_in[7];
    const float* pred_root_w= (const float*)d_in[8];
    const float* dec_rel_w  = (const float*)d_in[9];
    const float* dec_rel_b  = (const float*)d_in[10];
    const float* dec_root_w = (const float*)d_in[11];
    float* out = (float*)d_out;

    const int B = in_sizes[0] / ND;       // 524288, divisible by TPB
    const int blocks = B / TPB;
    gnn_kernel<<<blocks, TPB, 0, stream>>>(
        x, z, y, enc_rel_w, enc_rel_b, enc_root_w,
        pred_rel_w, pred_rel_b, pred_root_w,
        dec_rel_w, dec_rel_b, dec_root_w, out, B);
}

// Round 14
// 377.828 us; speedup vs baseline: 1.0952x; 1.0952x over previous
//
#include <hip/hip_runtime.h>

// nnmodel_35708358099045 R17: R14 (best, 141.5us) + hardware-pinned DEEP
// coalesced prefetch — the last untried matrix cell.
// Evidence: R16 (divergent+pinned-30-deep) proved the system is a saturated
// queue: per-wave lifetime 75K cy vs 6.5K dep-graph, waits consumed by
// queueing, more per-wave MLP useless. Logical service rate pins at
// ~3.0-3.5 TB/s for every structure vs 6.3 TB/s copy. R14 (coalesced) is
// 1-deep only because each LDS write implicitly vmcnt-waits the next line.
// R17: all 30 x/z loads issued up-front via asm (coalesced addresses
// unchanged), consumed per-group with literal vmcnt(20/16/12/8/4/0) +
// sched_barrier(0) (r263). Single-variable diff vs R14. FP order identical.
// Gates: WRITE 82-86MB (spill), FETCH 195-215MB, VGPR<=190.
// If ties ~141-147: service-rate ceiling confirmed -> ROOFLINE.

#define HN 10
#define ND 40
#define HF 8
#define TPB 256
#define WLEN 64
#define ROW4 11   // padded row stride in float4 (x / out staging)
#define ZROW 5    // padded z-slice stride in float4

#define GLD(dst, addr) \
    asm volatile("global_load_dwordx4 %0, %1, off" : "=v"(dst) : "v"(addr))
#define VMWAIT(n) do { \
    asm volatile("s_waitcnt vmcnt(" #n ")"); \
    __builtin_amdgcn_sched_barrier(0); } while (0)
#define LGKM0() do { \
    asm volatile("s_waitcnt lgkmcnt(0)" ::: "memory"); \
    __builtin_amdgcn_sched_barrier(0); } while (0)

__global__ __launch_bounds__(TPB) void gnn_kernel(
    const float* __restrict__ x,          // [B, 40]
    const float* __restrict__ z,          // [B, 10, 8]
    const float* __restrict__ y,          // [B, 40]
    const float* __restrict__ enc_rel_w,  // [8, 1]
    const float* __restrict__ enc_rel_b,  // [8]
    const float* __restrict__ enc_root_w, // [8, 8]
    const float* __restrict__ pred_rel_w, // [8, 8]
    const float* __restrict__ pred_rel_b, // [8]
    const float* __restrict__ pred_root_w,// [8, 8]
    const float* __restrict__ dec_rel_w,  // [1, 8]
    const float* __restrict__ dec_rel_b,  // [1]
    const float* __restrict__ dec_root_w, // [1, 1]
    float* __restrict__ out,              // [B, 40]
    int B)
{
    __shared__ float4 lds4[TPB * ROW4];   // 45056 B: 704 float4 per wave
    const int t  = threadIdx.x;
    const int l  = t & 63;
    const int wv = t >> 6;
    const long long W = (long long)blockIdx.x * TPB + wv * WLEN; // wave row base
    float4* wl = lds4 + wv * (WLEN * ROW4);

    const float w = 0.8948393168143698f;  // exp(-(1/3)^2) as fp32

    const float4* xg4 = (const float4*)x;   // row r = 10 float4 at r*10
    const float4* zg4 = (const float4*)z;   // row r = 20 float4 at r*20
    const float4* yg4 = (const float4*)y;
    float4*       og4 = (float4*)out;

    // ---- issue ALL x+z loads NOW (asm-pinned, coalesced addressing) ----
    const long long xw = W * 10 + l;          // lane's first x float4
    float4 X0, X1, X2, X3, X4, X5, X6, X7, X8, X9;
    GLD(X0, xg4 + xw +   0); GLD(X1, xg4 + xw +  64);
    GLD(X2, xg4 + xw + 128); GLD(X3, xg4 + xw + 192);
    GLD(X4, xg4 + xw + 256); GLD(X5, xg4 + xw + 320);
    GLD(X6, xg4 + xw + 384); GLD(X7, xg4 + xw + 448);
    GLD(X8, xg4 + xw + 512); GLD(X9, xg4 + xw + 576);

    const int  zbr = l >> 2, zm = l & 3;      // base row-in-wave, slot
    const long long zb = (W + zbr) * 20 + zm; // lane's z float4 base
    float4 ZA0, ZA1, ZA2, ZA3, ZB0, ZB1, ZB2, ZB3, ZC0, ZC1, ZC2, ZC3,
           ZD0, ZD1, ZD2, ZD3, ZE0, ZE1, ZE2, ZE3;
    GLD(ZA0, zg4 + zb +   0 +  0); GLD(ZA1, zg4 + zb + 320 +  0);
    GLD(ZA2, zg4 + zb + 640 +  0); GLD(ZA3, zg4 + zb + 960 +  0);
    GLD(ZB0, zg4 + zb +   0 +  4); GLD(ZB1, zg4 + zb + 320 +  4);
    GLD(ZB2, zg4 + zb + 640 +  4); GLD(ZB3, zg4 + zb + 960 +  4);
    GLD(ZC0, zg4 + zb +   0 +  8); GLD(ZC1, zg4 + zb + 320 +  8);
    GLD(ZC2, zg4 + zb + 640 +  8); GLD(ZC3, zg4 + zb + 960 +  8);
    GLD(ZD0, zg4 + zb +   0 + 12); GLD(ZD1, zg4 + zb + 320 + 12);
    GLD(ZD2, zg4 + zb + 640 + 12); GLD(ZD3, zg4 + zb + 960 + 12);
    GLD(ZE0, zg4 + zb +   0 + 16); GLD(ZE1, zg4 + zb + 320 + 16);
    GLD(ZE2, zg4 + zb + 640 + 16); GLD(ZE3, zg4 + zb + 960 + 16);
    // outstanding: 30 (x:10 oldest, then z grp A..E)

    const float drb   = dec_rel_b[0];
    const float droot = dec_root_w[0];

    auto enc_row = [&](float aggv, float4 v0, float4 v1, float (&r)[HF]) {
        float zrow[HF] = {v0.x, v0.y, v0.z, v0.w, v1.x, v1.y, v1.z, v1.w};
        #pragma unroll
        for (int f = 0; f < HF; ++f) {
            float acc = aggv * enc_rel_w[f] + enc_rel_b[f];
            #pragma unroll
            for (int g = 0; g < HF; ++g)
                acc += zrow[g] * enc_root_w[f * HF + g];
            r[f] = fmaxf(acc, 0.0f);
        }
    };

    auto emit = [&](const float (&rm)[HF], const float (&rc)[HF],
                    const float (&rp)[HF]) -> float {
        float a2[HF];
        #pragma unroll
        for (int f = 0; f < HF; ++f)
            a2[f] = rc[f] + w * (rm[f] + rp[f]);
        float s = 0.0f;
        #pragma unroll
        for (int f = 0; f < HF; ++f) {
            float acc = pred_rel_b[f];
            #pragma unroll
            for (int g = 0; g < HF; ++g)
                acc += a2[g] * pred_rel_w[f * HF + g];
            #pragma unroll
            for (int g = 0; g < HF; ++g)
                acc += rc[g] * pred_root_w[f * HF + g];
            s += fmaxf(acc, 0.0f) * dec_rel_w[f];
        }
        return s;
    };

    // ---- X phase: wait x (z stays in flight), stage to padded LDS ----
    VMWAIT(20);
    {
        auto put = [&](int k, float4 v) {
            int i = l + 64 * k; int r = i / 10, q = i - r * 10;
            wl[r * ROW4 + q] = v;
        };
        put(0, X0); put(1, X1); put(2, X2); put(3, X3); put(4, X4);
        put(5, X5); put(6, X6); put(7, X7); put(8, X8); put(9, X9);
    }
    LGKM0();

    // rolling-window transpose readback; aggs on the fly (no xv[40])
    float a_[10];
    {
        float4 prev = wl[l * ROW4 + 9];       // X9
        #pragma unroll
        for (int k = 0; k < 10; ++k) {
            float4 cur = wl[l * ROW4 + k];
            // FP order identical to R5-R16: X[k-1].y+z+w + X[k].x+y+z
            a_[k] = prev.y + prev.z + prev.w + cur.x + cur.y + cur.z;
            prev = cur;
        }
    }
    float u0 = a_[2], u1 = a_[3], u2 = a_[4], u3 = a_[5],
          u4 = a_[6], u5 = a_[7], u6 = a_[8], u7 = a_[9];

    // ---- z grp0 (nodes 0,1): wait, stage buf0, consume ----
    VMWAIT(16);
    wl[(zbr +  0) * ZROW + zm] = ZA0;
    wl[(zbr + 16) * ZROW + zm] = ZA1;
    wl[(zbr + 32) * ZROW + zm] = ZA2;
    wl[(zbr + 48) * ZROW + zm] = ZA3;
    LGKM0();
    float r0s[HF], r1s[HF];
    {
        float4 q0 = wl[l * ZROW + 0], q1 = wl[l * ZROW + 1],
               q2 = wl[l * ZROW + 2], q3 = wl[l * ZROW + 3];
        enc_row(a_[0], q0, q1, r0s);
        enc_row(a_[1], q2, q3, r1s);
    }
    float rm[HF], rc[HF];
    #pragma unroll
    for (int f = 0; f < HF; ++f) { rm[f] = r0s[f]; rc[f] = r1s[f]; }

    float t0 = 0.f, t1 = 0.f, t2 = 0.f, t3 = 0.f,
          t4 = 0.f, t5 = 0.f, t6 = 0.f, t7 = 0.f;

    // ---- z groups 1..4: literal-counted waits, dbuf stage, consume ----
    // (manually unrolled so vmcnt immediates are literals; shift-queue
    //  rotation kept identical to R14's loop body)
    #define ZSTEP(N, G0, G1, G2, G3, BUFOFF)                                \
    do {                                                                    \
        VMWAIT(N);                                                          \
        float4* bw = wl + (BUFOFF);                                         \
        bw[(zbr +  0) * ZROW + zm] = G0;                                    \
        bw[(zbr + 16) * ZROW + zm] = G1;                                    \
        bw[(zbr + 32) * ZROW + zm] = G2;                                    \
        bw[(zbr + 48) * ZROW + zm] = G3;                                    \
        LGKM0();                                                            \
        float4 q0 = bw[l * ZROW + 0], q1 = bw[l * ZROW + 1],                \
               q2 = bw[l * ZROW + 2], q3 = bw[l * ZROW + 3];                \
        float rp0[HF], rp1[HF];                                             \
        enc_row(u0, q0, q1, rp0);                                           \
        enc_row(u1, q2, q3, rp1);                                           \
        const float sA = emit(rm, rc, rp0);                                 \
        const float sB = emit(rc, rp0, rp1);                                \
        t0 = t2; t1 = t3; t2 = t4; t3 = t5; t4 = t6; t5 = t7;               \
        t6 = sA; t7 = sB;                                                   \
        u0 = u2; u1 = u3; u2 = u4; u3 = u5; u4 = u6; u5 = u7;               \
        _Pragma("unroll")                                                   \
        for (int f = 0; f < HF; ++f) { rm[f] = rp0[f]; rc[f] = rp1[f]; }    \
    } while (0)

    ZSTEP(12, ZB0, ZB1, ZB2, ZB3, WLEN * ZROW);   // j=1 -> buf1
    ZSTEP( 8, ZC0, ZC1, ZC2, ZC3, 0);             // j=2 -> buf0
    ZSTEP( 4, ZD0, ZD1, ZD2, ZD3, WLEN * ZROW);   // j=3 -> buf1
    ZSTEP( 0, ZE0, ZE1, ZE2, ZE3, 0);             // j=4 -> buf0
    #undef ZSTEP
    // rm=r[8], rc=r[9]; t0..t7 = s2[1..8]

    // ---- epilogue: y coalesced into named regs (fly under tail emits) ----
    float4 Y0 = yg4[xw +   0], Y1 = yg4[xw +  64], Y2 = yg4[xw + 128],
           Y3 = yg4[xw + 192], Y4 = yg4[xw + 256], Y5 = yg4[xw + 320],
           Y6 = yg4[xw + 384], Y7 = yg4[xw + 448], Y8 = yg4[xw + 512],
           Y9 = yg4[xw + 576];

    const float s9 = emit(rm, rc, r0s);       // s2[9]
    const float s0 = emit(rc, r0s, r1s);      // s2[0]

    // stage out partials in 11-pad layout, named scalars only
    auto stage_pair = [&](int k, float sa, float sb) {
        const float pair = sa + sb + drb;
        float4 vo;
        vo.x = sa + drb;
        vo.y = pair;
        vo.z = pair;
        vo.w = sb + drb;
        wl[l * ROW4 + k] = vo;                // conflict-free b128
    };
    stage_pair(0, s0, t0);
    stage_pair(1, t0, t1);
    stage_pair(2, t1, t2);
    stage_pair(3, t2, t3);
    stage_pair(4, t3, t4);
    stage_pair(5, t4, t5);
    stage_pair(6, t5, t6);
    stage_pair(7, t6, t7);
    stage_pair(8, t7, s9);
    stage_pair(9, s9, s0);
    LGKM0();

    // drain: coalesced full-line stores (merged 64B transactions)
    auto drain = [&](int k, float4 vy) {
        int i = l + 64 * k; int r = i / 10, q = i - r * 10;
        float4 p = wl[r * ROW4 + q];          // near-sequential, conflict-free
        p.x += vy.x * droot;
        p.y += vy.y * droot;
        p.z += vy.z * droot;
        p.w += vy.w * droot;
        og4[W * 10 + i] = p;
    };
    drain(0, Y0); drain(1, Y1); drain(2, Y2); drain(3, Y3); drain(4, Y4);
    drain(5, Y5); drain(6, Y6); drain(7, Y7); drain(8, Y8); drain(9, Y9);
}

extern "C" void kernel_launch(void* const* d_in, const int* in_sizes, int n_in,
                              void* d_out, int out_size, void* d_ws, size_t ws_size,
                              hipStream_t stream) {
    const float* x          = (const float*)d_in[0];
    const float* z          = (const float*)d_in[1];
    const float* y          = (const float*)d_in[2];
    const float* enc_rel_w  = (const float*)d_in[3];
    const float* enc_rel_b  = (const float*)d_in[4];
    const float* enc_root_w = (const float*)d_in[5];
    const float* pred_rel_w = (const float*)d_in[6];
    const float* pred_rel_b = (const float*)d_in[7];
    const float* pred_root_w= (const float*)d_in[8];
    const float* dec_rel_w  = (const float*)d_in[9];
    const float* dec_rel_b  = (const float*)d_in[10];
    const float* dec_root_w = (const float*)d_in[11];
    float* out = (float*)d_out;

    const int B = in_sizes[0] / ND;       // 524288, divisible by TPB
    const int blocks = B / TPB;           // 2048
    gnn_kernel<<<blocks, TPB, 0, stream>>>(
        x, z, y, enc_rel_w, enc_rel_b, enc_root_w,
        pred_rel_w, pred_rel_b, pred_root_w,
        dec_rel_w, dec_rel_b, dec_root_w, out, B);
}